// Round 10
// baseline (194.935 us; speedup 1.0000x reference)
//
#include <hip/hip_runtime.h>
#include <hip/hip_bf16.h>

// GraphSAGE 2-layer forward. N=100000, E=1250000, 64 -> 64 -> 32, fp32.
//
// Round-23: round-22 (190.7us) + zero-row sentinel. agg64's VALUBusy hit 54%
// with ~48 per-element cndmask selects per gather iteration (the `c?x:0`
// masking). Fix: t1n/t2n get a zeroed row at index N (written by the pack
// block); out-of-range gathers redirect the INDEX to N (1 cndmask per row)
// and accumulation is unconditional. Adding conv(0)=+0.0f is bit-identical
// to the old select. Same in agg32. All else = round-22.
// Pipeline: memset(gcursor) -> [dense1(LDS) || p1 || w2p-pack+zero-rows]
//           -> p2 -> agg64_d2 (3-deep, no selects) -> agg32 (3-deep, same).

#define NF 64
#define BW 256            // bucket width (nodes); rel = dst & 255
#define BSH 8
#define MAXB 512          // max buckets (LDS arrays)
#define CAPMAX 8192       // max edges per bucket region (mean 3197)
#define P1_CHUNK 2048
#define H1S 68            // h1s row stride in floats

typedef __attribute__((ext_vector_type(8))) short short8;
typedef __attribute__((ext_vector_type(8))) unsigned short ushort8v;
typedef __attribute__((ext_vector_type(4))) float floatx4;

__device__ __forceinline__ short bf16hi(float v) {
    __hip_bfloat16 h = __float2bfloat16(v);
    return *(short*)&h;
}
__device__ __forceinline__ float bf2f(short s) {
    __hip_bfloat16 h = *(__hip_bfloat16*)&s;
    return __bfloat162float(h);
}
__device__ __forceinline__ float bits2f(unsigned short u) {
    unsigned int x = ((unsigned int)u) << 16;
    union { unsigned int i; float f; } c; c.i = x; return c.f;
}

// ---------------- dispatch A: dense1 (LDS-staged) || p1 || w2p pack ----------
// Blocks [0, dblocks): dense1 full 128-col (bufA=x@Ws1+b1, t1n=bf16(x@Wn1)),
//   weights staged per block into 36.8KB LDS (round-13 proven body).
// Blocks [dblocks, packBase): p1 bucketing (4KB of the union).
// Blocks [packBase, packBase+4): pack w2p; part 0 also zeroes the sentinel
//   rows t1n[N][:] and t2n[N][:] (consumed only by later dispatches).

__global__ __launch_bounds__(256) void d1p1_kernel(
        const int* __restrict__ src, const int* __restrict__ dst,
        int* __restrict__ gcursor, unsigned* __restrict__ bucket,
        int E, int nbuckets, int dblocks, int packBase,
        const float* __restrict__ X,                 // [N][64]
        const float* __restrict__ Wself,             // [64][64] k-major
        const float* __restrict__ Wneigh,            // [64][64] k-major
        const float* __restrict__ bias,              // [64]
        float* __restrict__ outA,                    // [N][64] f32 (xs)
        unsigned short* __restrict__ outB,           // [N+1][64] bf16 bits (t1n)
        int N,
        const float* __restrict__ Ws2,               // [64][32] k-major
        const float* __restrict__ Wn2,               // [64][32] k-major
        unsigned short* __restrict__ w2p,            // [8192] dense2 pack hi/lo
        unsigned short* __restrict__ t2z) {          // t2n base (for sentinel row)
    __shared__ __align__(16) int smem_i[9216];       // 36864 B union
    const int tid = threadIdx.x;

    if ((int)blockIdx.x >= packBase) {
        // ---------------- pack w2p + zero sentinel rows ----------------
        const int part = blockIdx.x - packBase;      // 0..3
        for (int i = tid; i < 16 * 64; i += 256) {   // 16 cols per part
            int n = part * 16 + (i >> 6), k = i & 63;
            float v = (n < 32) ? Ws2[k * 32 + n] : Wn2[k * 32 + (n - 32)];
            short hv = bf16hi(v);
            w2p[n * 64 + k] = (unsigned short)hv;
            w2p[4096 + n * 64 + k] = (unsigned short)bf16hi(v - bf2f(hv));
        }
        if (part == 0) {                             // zero rows at index N
            if (tid < 64) outB[(size_t)N * 64 + tid] = 0;
            if (tid >= 64 && tid < 96) t2z[(size_t)N * 32 + (tid - 64)] = 0;
        }
        return;
    }

    if ((int)blockIdx.x >= dblocks) {
        // ---------------- p1: bucket the edge list ----------------
        int* cnt   = smem_i;                         // [MAXB]
        int* cbase = smem_i + MAXB;                  // [MAXB]
        const int bid = blockIdx.x - dblocks;
        const int beg = bid * P1_CHUNK;
        const int end = min(E, beg + P1_CHUNK);
        for (int i = tid; i < nbuckets; i += 256) cnt[i] = 0;
        __syncthreads();
        for (int e = beg + tid; e < end; e += 256)
            atomicAdd(&cnt[dst[e] >> BSH], 1);
        __syncthreads();
        for (int i = tid; i < nbuckets; i += 256) {
            int c = cnt[i];
            cbase[i] = c ? atomicAdd(&gcursor[i], c) : 0;
            cnt[i] = 0;                              // reuse as local cursor
        }
        __syncthreads();
        for (int e = beg + tid; e < end; e += 256) {
            int d = dst[e];
            int r = d >> BSH;
            int p = cbase[r] + atomicAdd(&cnt[r], 1);
            if (p < CAPMAX)                          // clamp: no OOB even if skewed
                bucket[(size_t)r * CAPMAX + p] = ((unsigned)src[e] << BSH) | (unsigned)(d & (BW - 1));
        }
        return;
    }

    // ---------------- dense1: [N][64] @ [64][128] MFMA split-bf16 ----------
    // A: A[m=lane&15][k=(lane>>4)*8+j]; C/D: col=lane&15, row=(lane>>4)*4+reg.
    constexpr int NT = 8, NSELF = 4, NO = 128, HALF = 64;
    unsigned short* wh = (unsigned short*)smem_i;            // [NO*72]
    unsigned short* wl = wh + NO * 72;                       // [NO*72]
    for (int i = tid; i < NO * 64; i += 256) {
        int n = i & (NO - 1), k = i / NO;            // consecutive tid -> coalesced
        float v = (n < HALF) ? Wself[k * HALF + n] : Wneigh[k * HALF + (n - HALF)];
        short hv = bf16hi(v);
        wh[n * 72 + k] = (unsigned short)hv;
        wl[n * 72 + k] = (unsigned short)bf16hi(v - bf2f(hv));
    }

    const int lane = tid & 63;
    const int wid  = tid >> 6;
    const int m = lane & 15, quad = lane >> 4;
    const int rowblk = blockIdx.x * 128 + wid * 32;

    floatx4 acc[2][NT];
    #pragma unroll
    for (int rt = 0; rt < 2; ++rt)
        #pragma unroll
        for (int t = 0; t < NT; ++t) acc[rt][t] = (floatx4)(0.f);

    short8 ah[2][2], al[2][2];   // [rowset][k-half]
    #pragma unroll
    for (int rt = 0; rt < 2; ++rt) {
        int r = rowblk + rt * 16 + m;
        if (r >= N) r = N - 1;                       // clamped load, store guarded
        const float* xp = X + (size_t)r * 64 + quad * 8;
        #pragma unroll
        for (int h = 0; h < 2; ++h) {
            floatx4 f0 = *(const floatx4*)(xp + h * 32);
            floatx4 f1 = *(const floatx4*)(xp + h * 32 + 4);
            short8 hi, lo;
            #pragma unroll
            for (int j = 0; j < 4; ++j) {
                short hv = bf16hi(f0[j]);
                hi[j] = hv; lo[j] = bf16hi(f0[j] - bf2f(hv));
                short hv2 = bf16hi(f1[j]);
                hi[4 + j] = hv2; lo[4 + j] = bf16hi(f1[j] - bf2f(hv2));
            }
            ah[rt][h] = hi; al[rt][h] = lo;
        }
    }
    __syncthreads();                                 // weights staged

    #pragma unroll
    for (int t = 0; t < NT; ++t) {
        int n = t * 16 + m;
        const unsigned short* ph = wh + n * 72 + quad * 8;
        const unsigned short* pl = wl + n * 72 + quad * 8;
        #pragma unroll
        for (int h = 0; h < 2; ++h) {
            short8 bh = *(const short8*)(ph + h * 32);
            short8 bl = *(const short8*)(pl + h * 32);
            #pragma unroll
            for (int rt = 0; rt < 2; ++rt) {
                acc[rt][t] = __builtin_amdgcn_mfma_f32_16x16x32_bf16(ah[rt][h], bh, acc[rt][t], 0, 0, 0);
                acc[rt][t] = __builtin_amdgcn_mfma_f32_16x16x32_bf16(al[rt][h], bh, acc[rt][t], 0, 0, 0);
                acc[rt][t] = __builtin_amdgcn_mfma_f32_16x16x32_bf16(ah[rt][h], bl, acc[rt][t], 0, 0, 0);
            }
        }
    }

    #pragma unroll
    for (int rt = 0; rt < 2; ++rt) {
        #pragma unroll
        for (int t = 0; t < NT; ++t) {
            #pragma unroll
            for (int r4 = 0; r4 < 4; ++r4) {
                int row = rowblk + rt * 16 + quad * 4 + r4;
                if (row < N) {
                    if (t < NSELF) {
                        int col = t * 16 + m;
                        outA[(size_t)row * 64 + col] = acc[rt][t][r4] + bias[col];
                    } else {
                        int col = (t - NSELF) * 16 + m;
                        outB[(size_t)row * 64 + col] = (unsigned short)bf16hi(acc[rt][t][r4]);
                    }
                }
            }
        }
    }
}

// ---------------- p2: per-bucket CSR (exclusive window) ----------------

__global__ __launch_bounds__(256) void p2_csr_kernel(const unsigned* __restrict__ bucket,
                                                     const int* __restrict__ gcursor,
                                                     int* __restrict__ row_start,
                                                     int* __restrict__ csr_src,
                                                     int N, int nbuckets) {
    __shared__ unsigned stage[CAPMAX];   // 32 KB
    __shared__ int cnt[BW];
    __shared__ int excl[BW];
    const int r = blockIdx.x;
    const int tid = threadIdx.x;

    // base = sum_{i<r} min(gcursor[i], CAPMAX)   (excl[] as scratch)
    int partial = 0;
    for (int i = tid; i < r; i += 256) partial += min(gcursor[i], CAPMAX);
    excl[tid] = partial;
    __syncthreads();
    for (int off = 128; off > 0; off >>= 1) {
        if (tid < off) excl[tid] += excl[tid + off];
        __syncthreads();
    }
    const int base = excl[0];
    const int sz = min(gcursor[r], CAPMAX);
    const unsigned* bsrc = bucket + (size_t)r * CAPMAX;
    __syncthreads();

    cnt[tid] = 0;
    __syncthreads();
    for (int i = tid; i < sz; i += 256) {
        unsigned v = bsrc[i];
        stage[i] = v;
        atomicAdd(&cnt[v & (BW - 1)], 1);
    }
    __syncthreads();
    // inclusive scan (Hillis-Steele, 1 elem/thread since BW == blockDim)
    excl[tid] = cnt[tid];
    __syncthreads();
    for (int off = 1; off < BW; off <<= 1) {
        int v0 = (tid >= off) ? excl[tid - off] : 0;
        __syncthreads();
        excl[tid] += v0;
        __syncthreads();
    }
    int node = r * BW + tid;
    if (node < N) row_start[node] = base + excl[tid] - cnt[tid];
    if (r == nbuckets - 1 && tid == 0) row_start[N] = base + sz;
    __syncthreads();
    cnt[tid] = excl[tid] - cnt[tid];             // exclusive cursors
    __syncthreads();
    for (int i = tid; i < sz; i += 256) {
        unsigned v = stage[i];
        int p = atomicAdd(&cnt[v & (BW - 1)], 1);
        csr_src[base + p] = (int)(v >> BSH);     // window owned by this block only
    }
}

// ---------------- fused agg64 + dense2 (3-deep, zero-row sentinel) ----------
// Block = 16 nodes, 4 waves. Half-wave owns TWO nodes; 3-deep per node =
// 6 concurrent row gathers per lane; out-of-range rows redirect to the
// zeroed sentinel row N (1 cndmask per row, unconditional accumulate).

__global__ __launch_bounds__(256) void agg64_d2_kernel(
        const unsigned short* __restrict__ t1n,      // [N+1][64] bf16 bits
        const float* __restrict__ xs,                // [N][64] self+bias
        const int* __restrict__ row_start,
        const int* __restrict__ csr_src,
        const unsigned short* __restrict__ w2p,      // packed hi/lo fragments
        const float* __restrict__ b2,                // [32]
        float* __restrict__ outD,                    // [N][32] (d_out)
        unsigned short* __restrict__ t2n,            // [N+1][32] bf16 bits
        int N, int E) {
    __shared__ float h1s[16][H1S];                   // 4.25 KB, padded stride
    const int tid = threadIdx.x;
    const int lane = tid & 63;
    const int wid  = tid >> 6;
    const int half = lane >> 5;                      // node select within pair
    const int g = (lane >> 3) & 3;                   // 4 groups of 8 per node
    const int c = lane & 7;
    const int nbase = blockIdx.x * 16;

    const int ln0 = wid * 4 + half;                  // this half-wave's 2 nodes
    const int ln1 = ln0 + 2;
    const int n0 = nbase + ln0, n1 = nbase + ln1;
    int beg0 = 0, end0 = 0, beg1 = 0, end1 = 0;
    if (n0 < N) { beg0 = row_start[n0]; end0 = row_start[n0 + 1]; }
    if (n1 < N) { beg1 = row_start[n1]; end1 = row_start[n1 + 1]; }

    float a0[8] = {0.f, 0.f, 0.f, 0.f, 0.f, 0.f, 0.f, 0.f};
    float a1[8] = {0.f, 0.f, 0.f, 0.f, 0.f, 0.f, 0.f, 0.f};
    int j0 = beg0 + g, j1 = beg1 + g;
    const int Em1 = E - 1;
    // prefetched index set for the current iteration (3 per node)
    int i0 = csr_src[min(j0, Em1)];
    int i1 = csr_src[min(j0 + 4, Em1)];
    int i2 = csr_src[min(j0 + 8, Em1)];
    int i3 = csr_src[min(j1, Em1)];
    int i4 = csr_src[min(j1 + 4, Em1)];
    int i5 = csr_src[min(j1 + 8, Em1)];
    while ((j0 < end0) || (j1 < end1)) {
        // redirect out-of-range rows to zeroed sentinel row N (1 cndmask each)
        int s0 = (j0     < end0) ? i0 : N;
        int s1 = (j0 + 4 < end0) ? i1 : N;
        int s2 = (j0 + 8 < end0) ? i2 : N;
        int s3 = (j1     < end1) ? i3 : N;
        int s4 = (j1 + 4 < end1) ? i4 : N;
        int s5 = (j1 + 8 < end1) ? i5 : N;
        // 6 concurrent row gathers
        ushort8v u0 = *(const ushort8v*)(t1n + (size_t)s0 * 64 + c * 8);
        ushort8v u1 = *(const ushort8v*)(t1n + (size_t)s1 * 64 + c * 8);
        ushort8v u2 = *(const ushort8v*)(t1n + (size_t)s2 * 64 + c * 8);
        ushort8v u3 = *(const ushort8v*)(t1n + (size_t)s3 * 64 + c * 8);
        ushort8v u4 = *(const ushort8v*)(t1n + (size_t)s4 * 64 + c * 8);
        ushort8v u5 = *(const ushort8v*)(t1n + (size_t)s5 * 64 + c * 8);
        // prefetch next iteration's indices (overlap gather latency)
        i0 = csr_src[min(j0 + 12, Em1)];
        i1 = csr_src[min(j0 + 16, Em1)];
        i2 = csr_src[min(j0 + 20, Em1)];
        i3 = csr_src[min(j1 + 12, Em1)];
        i4 = csr_src[min(j1 + 16, Em1)];
        i5 = csr_src[min(j1 + 20, Em1)];
        #pragma unroll
        for (int i = 0; i < 8; ++i) {                // unconditional: +0.0f when masked
            a0[i] += bits2f(u0[i]) + bits2f(u1[i]) + bits2f(u2[i]);
            a1[i] += bits2f(u3[i]) + bits2f(u4[i]) + bits2f(u5[i]);
        }
        j0 += 12; j1 += 12;
    }

    // issue tail loads now; latency hides under reduce + h1s + barrier
    const int m = lane & 15, quad = lane >> 4;
    const int coln = wid * 16 + m;
    const unsigned short* pb = w2p + coln * 64 + quad * 8;
    short8 bhf0 = *(const short8*)(pb);
    short8 bhf1 = *(const short8*)(pb + 32);
    short8 blf0 = *(const short8*)(pb + 4096);
    short8 blf1 = *(const short8*)(pb + 4096 + 32);

    floatx4 x00 = (floatx4)(0.f), x01 = (floatx4)(0.f);
    floatx4 x10 = (floatx4)(0.f), x11 = (floatx4)(0.f);
    if (g == 0) {
        if (n0 < N) {
            const float* p = xs + (size_t)n0 * 64 + c * 8;
            x00 = *(const floatx4*)p; x01 = *(const floatx4*)(p + 4);
        }
        if (n1 < N) {
            const float* p = xs + (size_t)n1 * 64 + c * 8;
            x10 = *(const floatx4*)p; x11 = *(const floatx4*)(p + 4);
        }
    }

    #pragma unroll
    for (int i = 0; i < 8; ++i) {                    // reduce over 4 groups (in-half)
        float v = a0[i];
        v += __shfl_xor(v, 8);
        v += __shfl_xor(v, 16);
        a0[i] = v;
        float w = a1[i];
        w += __shfl_xor(w, 8);
        w += __shfl_xor(w, 16);
        a1[i] = w;
    }
    if (g == 0) {                                    // 8 lanes per half write rows
        floatx4 h0, h1v;
        if (n0 < N) {
            float invd = 1.0f / fmaxf((float)(end0 - beg0), 1.0f);
            #pragma unroll
            for (int i = 0; i < 4; ++i) {
                h0[i]  = fmaxf(x00[i] + a0[i] * invd, 0.f);
                h1v[i] = fmaxf(x01[i] + a0[4 + i] * invd, 0.f);
            }
        } else { h0 = (floatx4)(0.f); h1v = (floatx4)(0.f); }
        *(floatx4*)&h1s[ln0][c * 8]     = h0;
        *(floatx4*)&h1s[ln0][c * 8 + 4] = h1v;
        if (n1 < N) {
            float invd = 1.0f / fmaxf((float)(end1 - beg1), 1.0f);
            #pragma unroll
            for (int i = 0; i < 4; ++i) {
                h0[i]  = fmaxf(x10[i] + a1[i] * invd, 0.f);
                h1v[i] = fmaxf(x11[i] + a1[4 + i] * invd, 0.f);
            }
        } else { h0 = (floatx4)(0.f); h1v = (floatx4)(0.f); }
        *(floatx4*)&h1s[ln1][c * 8]     = h0;
        *(floatx4*)&h1s[ln1][c * 8 + 4] = h1v;
    }
    __syncthreads();                                 // h1 tile ready

    // dense2: wave wid -> output cols wid*16 .. wid*16+15
    short8 ah[2], al[2];                             // A = h1s, split hi/lo
    #pragma unroll
    for (int h = 0; h < 2; ++h) {
        const float* hp = &h1s[m][quad * 8 + h * 32];
        floatx4 f0 = *(const floatx4*)hp;
        floatx4 f1 = *(const floatx4*)(hp + 4);
        short8 hi, lo;
        #pragma unroll
        for (int j = 0; j < 4; ++j) {
            short hv = bf16hi(f0[j]);
            hi[j] = hv; lo[j] = bf16hi(f0[j] - bf2f(hv));
            short hv2 = bf16hi(f1[j]);
            hi[4 + j] = hv2; lo[4 + j] = bf16hi(f1[j] - bf2f(hv2));
        }
        ah[h] = hi; al[h] = lo;
    }
    floatx4 acc2 = (floatx4)(0.f);
    acc2 = __builtin_amdgcn_mfma_f32_16x16x32_bf16(ah[0], bhf0, acc2, 0, 0, 0);
    acc2 = __builtin_amdgcn_mfma_f32_16x16x32_bf16(al[0], bhf0, acc2, 0, 0, 0);
    acc2 = __builtin_amdgcn_mfma_f32_16x16x32_bf16(ah[0], blf0, acc2, 0, 0, 0);
    acc2 = __builtin_amdgcn_mfma_f32_16x16x32_bf16(ah[1], bhf1, acc2, 0, 0, 0);
    acc2 = __builtin_amdgcn_mfma_f32_16x16x32_bf16(al[1], bhf1, acc2, 0, 0, 0);
    acc2 = __builtin_amdgcn_mfma_f32_16x16x32_bf16(ah[1], blf1, acc2, 0, 0, 0);
    #pragma unroll
    for (int r4 = 0; r4 < 4; ++r4) {
        int node = nbase + quad * 4 + r4;
        if (node < N) {
            if (coln < 32) outD[(size_t)node * 32 + coln] = acc2[r4] + b2[coln];
            else t2n[(size_t)node * 32 + (coln - 32)] = (unsigned short)bf16hi(acc2[r4]);
        }
    }
}

// ---------------- agg32: d_out += mean t2n[src], in place (3-deep) ----------
// 16-lane group per node (4 edge-groups x 3-deep), zero-row sentinel.

__global__ __launch_bounds__(256) void agg32_kernel(float* io,  // [N][32] (d_out)
                                                    const unsigned short* __restrict__ t2n,
                                                    const int* __restrict__ row_start,
                                                    const int* __restrict__ csr_src,
                                                    int N, int E) {
    const int tid = threadIdx.x;
    const int lane = tid & 63;
    const int wid = tid >> 6;
    const int slot = lane >> 4;                      // 4 nodes per wave
    const int g = (lane >> 2) & 3;                   // 4 edge-groups per node
    const int c = lane & 3;                          // 16B chunk of 64B row
    const int n = blockIdx.x * 16 + wid * 4 + slot;

    int beg = 0, end = 0;
    if (n < N) { beg = row_start[n]; end = row_start[n + 1]; }

    // hoist in-place read: overlaps the gather chain instead of trailing it
    floatx4 s0v = (floatx4)(0.f), s1v = (floatx4)(0.f);
    size_t o = (size_t)n * 32 + c * 8;
    if (n < N && g == 0) {
        s0v = *(const floatx4*)(io + o);
        s1v = *(const floatx4*)(io + o + 4);
    }

    float acc[8] = {0.f, 0.f, 0.f, 0.f, 0.f, 0.f, 0.f, 0.f};
    const int Em1 = E - 1;
    for (int j = beg + g; j < end; j += 12) {
        int r0 = csr_src[j];                         // j < end <= E guaranteed
        int r1 = csr_src[min(j + 4, Em1)];
        int r2 = csr_src[min(j + 8, Em1)];
        int s0 = r0;                                 // always in range
        int s1 = (j + 4 < end) ? r1 : N;             // sentinel redirect
        int s2 = (j + 8 < end) ? r2 : N;
        ushort8v u0 = *(const ushort8v*)(t2n + (size_t)s0 * 32 + c * 8);
        ushort8v u1 = *(const ushort8v*)(t2n + (size_t)s1 * 32 + c * 8);
        ushort8v u2 = *(const ushort8v*)(t2n + (size_t)s2 * 32 + c * 8);
        #pragma unroll
        for (int i = 0; i < 8; ++i)                  // unconditional accumulate
            acc[i] += bits2f(u0[i]) + bits2f(u1[i]) + bits2f(u2[i]);
    }
    #pragma unroll
    for (int i = 0; i < 8; ++i) {                    // reduce over 4 groups (16-lane)
        float v = acc[i];
        v += __shfl_xor(v, 4);
        v += __shfl_xor(v, 8);
        acc[i] = v;
    }
    if (n < N && g == 0) {
        float inv = 1.0f / fmaxf((float)(end - beg), 1.0f);
        floatx4 r0, r1;
        #pragma unroll
        for (int i = 0; i < 4; ++i) {
            r0[i] = s0v[i] + acc[i] * inv;
            r1[i] = s1v[i] + acc[4 + i] * inv;
        }
        *(floatx4*)(io + o) = r0;
        *(floatx4*)(io + o + 4) = r1;
    }
}

// ---------------- fallback (round-2 atomic path) ----------------

__global__ __launch_bounds__(256) void deg_kernel(const int* __restrict__ dst,
                                                  float* __restrict__ deg, int E) {
    int e = blockIdx.x * blockDim.x + threadIdx.x;
    if (e < E) atomicAdd(&deg[dst[e]], 1.0f);
}

__global__ __launch_bounds__(256) void agg_atomic_kernel(const float* __restrict__ feats,
                                                         const int* __restrict__ src,
                                                         const int* __restrict__ dst,
                                                         float* __restrict__ agg, int E) {
    int tid = blockIdx.x * blockDim.x + threadIdx.x;
    if (tid >= E * NF) return;
    int e = tid >> 6, f = tid & 63;
    atomicAdd(&agg[(size_t)dst[e] * NF + f], feats[(size_t)src[e] * NF + f]);
}

__global__ __launch_bounds__(256) void layer1_fb_kernel(const float* __restrict__ x,
                                                        const float* __restrict__ agg,
                                                        const float* __restrict__ deg,
                                                        const float* __restrict__ Wself,
                                                        const float* __restrict__ Wneigh,
                                                        const float* __restrict__ b,
                                                        float* __restrict__ h1, int N) {
    int tid = blockIdx.x * blockDim.x + threadIdx.x;
    if (tid >= N * NF) return;
    int n = tid >> 6, c = tid & 63;
    float inv = 1.0f / fmaxf(deg[n], 1.0f);
    const float* xrow = x + (size_t)n * NF;
    const float* arow = agg + (size_t)n * NF;
    float acc = b[c];
    #pragma unroll
    for (int k = 0; k < NF; ++k) {
        acc += xrow[k] * Wself[k * NF + c];
        acc += (arow[k] * inv) * Wneigh[k * NF + c];
    }
    h1[tid] = fmaxf(acc, 0.f);
}

__global__ __launch_bounds__(256) void layer2_fb_kernel(const float* __restrict__ h1,
                                                        const float* __restrict__ agg,
                                                        const float* __restrict__ deg,
                                                        const float* __restrict__ Wself,
                                                        const float* __restrict__ Wneigh,
                                                        const float* __restrict__ b,
                                                        float* __restrict__ out, int N) {
    int tid = blockIdx.x * blockDim.x + threadIdx.x;
    if (tid >= N * 32) return;
    int n = tid >> 5, c = tid & 31;
    float inv = 1.0f / fmaxf(deg[n], 1.0f);
    const float* hrow = h1 + (size_t)n * NF;
    const float* arow = agg + (size_t)n * NF;
    float acc = b[c];
    #pragma unroll
    for (int k = 0; k < NF; ++k) {
        acc += hrow[k] * Wself[k * 32 + c];
        acc += (arow[k] * inv) * Wneigh[k * 32 + c];
    }
    out[tid] = acc;
}

// ---------------- launch ----------------

extern "C" void kernel_launch(void* const* d_in, const int* in_sizes, int n_in,
                              void* d_out, int out_size, void* d_ws, size_t ws_size,
                              hipStream_t stream) {
    const float* x        = (const float*)d_in[0];
    const int*   src      = (const int*)d_in[1];
    const int*   dst      = (const int*)d_in[2];
    const float* W_self1  = (const float*)d_in[3];
    const float* W_neigh1 = (const float*)d_in[4];
    const float* b1       = (const float*)d_in[5];
    const float* W_self2  = (const float*)d_in[6];
    const float* W_neigh2 = (const float*)d_in[7];
    const float* b2       = (const float*)d_in[8];
    float* out = (float*)d_out;

    const int N = in_sizes[0] / NF;          // 100000
    const int E = in_sizes[1];               // 1250000
    const int nbuckets = (N + BW - 1) / BW;  // 391

    // ws layout; gather tables 128B-aligned (round-10 proven). t1n/t2n have
    // one extra SENTINEL row at index N (zeroed by pack block).
    const size_t rsPad = ((size_t)N + 8) & ~7ull;
    int* gcursor   = (int*)d_ws;                      // [MAXB]
    unsigned short* w2p = (unsigned short*)(gcursor + MAXB);  // [8192] (16 KB)
    int* row_start = (int*)(w2p + 8192);              // [N+1] padded
    int* csr_src   = row_start + rsPad;               // [E]
    uintptr_t pa = (uintptr_t)(csr_src + (((size_t)E + 7) & ~7ull));
    pa = (pa + 127) & ~(uintptr_t)127;                // 128B align
    float* bufA = (float*)pa;                         // [N][64] f32 (xs)
    unsigned* bucket = (unsigned*)bufA;               // alias (serialized fallback only)
    unsigned short* t1n = (unsigned short*)(bufA + (size_t)N * NF);  // [N+1][64] bf16
    unsigned short* t2n = t1n + (size_t)(N + 1) * NF;                // [N+1][32] bf16
    size_t need = (size_t)((char*)(t2n + (size_t)(N + 1) * 32) - (char*)d_ws);

    bool fast = ws_size >= need
             && E > 0 && N > 0
             && nbuckets <= MAXB
             && (size_t)nbuckets * CAPMAX <= (size_t)N * NF
             && (size_t)E * 2 / (size_t)nbuckets <= CAPMAX
             && N < (1 << 24)
             && out_size >= N * 32;

    if (fast) {
        const int dblocks  = (N + 127) / 128;                    // 782
        const int p1blocks = (E + P1_CHUNK - 1) / P1_CHUNK;      // 611
        unsigned* bucket2 = (unsigned*)((uintptr_t)(t2n + (size_t)(N + 1) * 32 + 31) & ~(uintptr_t)63);
        bucket2 = (unsigned*)(((uintptr_t)(t2n + (size_t)(N + 1) * 32) + 63) & ~(uintptr_t)63);
        size_t need2 = (size_t)((char*)(bucket2 + (size_t)nbuckets * CAPMAX) - (char*)d_ws);
        hipMemsetAsync(gcursor, 0, MAXB * sizeof(int), stream);
        if (ws_size >= need2) {
            // fused: dense1 || p1 || pack in one dispatch (disjoint bucket2)
            d1p1_kernel<<<dblocks + p1blocks + 4, 256, 0, stream>>>(
                src, dst, gcursor, bucket2, E, nbuckets, dblocks,
                dblocks + p1blocks,
                x, W_self1, W_neigh1, b1, bufA, t1n, N,
                W_self2, W_neigh2, w2p, t2n);
            p2_csr_kernel<<<nbuckets, 256, 0, stream>>>(bucket2, gcursor,
                                                        row_start, csr_src, N, nbuckets);
        } else {
            // tight ws: p1+pack first (bucket aliases bufA), then p2, then dense1
            d1p1_kernel<<<p1blocks + 4, 256, 0, stream>>>(
                src, dst, gcursor, bucket, E, nbuckets, 0, p1blocks,
                x, W_self1, W_neigh1, b1, bufA, t1n, N,
                W_self2, W_neigh2, w2p, t2n);
            p2_csr_kernel<<<nbuckets, 256, 0, stream>>>(bucket, gcursor,
                                                        row_start, csr_src, N, nbuckets);
            d1p1_kernel<<<dblocks, 256, 0, stream>>>(
                src, dst, gcursor, bucket, E, nbuckets, dblocks,
                dblocks + p1blocks,                  // unreachable: no pack blocks
                x, W_self1, W_neigh1, b1, bufA, t1n, N,
                W_self2, W_neigh2, w2p, t2n);
        }
        agg64_d2_kernel<<<(N + 15) / 16, 256, 0, stream>>>(
            t1n, bufA, row_start, csr_src, w2p, b2, out, t2n, N, E);
        agg32_kernel<<<(N + 15) / 16, 256, 0, stream>>>(out, t2n,
                                                        row_start, csr_src, N, E);
    } else {
        // fallback: atomic path (~51.6 MB)
        float* deg = (float*)d_ws;
        float* agg = deg + N;
        float* h1  = agg + (size_t)N * NF;
        hipMemsetAsync(deg, 0, (size_t)(N + (size_t)N * NF) * sizeof(float), stream);
        deg_kernel<<<(E + 255) / 256, 256, 0, stream>>>(dst, deg, E);
        int at = E * NF;
        agg_atomic_kernel<<<(at + 255) / 256, 256, 0, stream>>>(x, src, dst, agg, E);
        layer1_fb_kernel<<<(N * NF + 255) / 256, 256, 0, stream>>>(x, agg, deg, W_self1,
                                                                   W_neigh1, b1, h1, N);
        hipMemsetAsync(agg, 0, (size_t)N * NF * sizeof(float), stream);
        agg_atomic_kernel<<<(at + 255) / 256, 256, 0, stream>>>(h1, src, dst, agg, E);
        layer2_fb_kernel<<<(N * 32 + 255) / 256, 256, 0, stream>>>(h1, agg, deg, W_self2,
                                                                   W_neigh2, b2, out, N);
    }
}

// Round 11
// 189.187 us; speedup vs baseline: 1.0304x; 1.0304x over previous
//
#include <hip/hip_runtime.h>
#include <hip/hip_bf16.h>

// GraphSAGE 2-layer forward. N=100000, E=1250000, 64 -> 64 -> 32, fp32.
//
// Round-24: round-23 + in-place CSR. p2 no longer compacts across buckets:
// bases are bucket-region-fixed (r*CAPMAX), per-node extents stored as
// rowext[n] = int2{beg,end} (one 8B load in agg kernels). The sorted src
// ids are scattered back INTO the bucket region (LDS-staged, barrier'd ->
// in-place safe), deleting the csr_src array (+5MB RFO) and p2's inline
// cross-bucket prefix (up to 391 global reads + 2 log-trees per block).
// agg64 keeps the round-23 zero-row sentinel (t1n/t2n row N zeroed).
// Pipeline: memset(gcursor) -> [dense1(LDS) || p1 || w2p-pack+zero-rows]
//           -> p2 (in-place) -> agg64_d2 (3-deep) -> agg32 (3-deep).

#define NF 64
#define BW 256            // bucket width (nodes); rel = dst & 255
#define BSH 8
#define MAXB 512          // max buckets (LDS arrays)
#define CAPMAX 8192       // max edges per bucket region (mean 3197)
#define P1_CHUNK 2048
#define H1S 68            // h1s row stride in floats

typedef __attribute__((ext_vector_type(8))) short short8;
typedef __attribute__((ext_vector_type(8))) unsigned short ushort8v;
typedef __attribute__((ext_vector_type(4))) float floatx4;
typedef __attribute__((ext_vector_type(2))) int intx2;

__device__ __forceinline__ short bf16hi(float v) {
    __hip_bfloat16 h = __float2bfloat16(v);
    return *(short*)&h;
}
__device__ __forceinline__ float bf2f(short s) {
    __hip_bfloat16 h = *(__hip_bfloat16*)&s;
    return __bfloat162float(h);
}
__device__ __forceinline__ float bits2f(unsigned short u) {
    unsigned int x = ((unsigned int)u) << 16;
    union { unsigned int i; float f; } c; c.i = x; return c.f;
}

// ---------------- dispatch A: dense1 (LDS-staged) || p1 || w2p pack ----------
// Blocks [0, dblocks): dense1 full 128-col (bufA=x@Ws1+b1, t1n=bf16(x@Wn1)),
//   weights staged per block into 36.8KB LDS (round-13 proven body).
// Blocks [dblocks, packBase): p1 bucketing (4KB of the union).
// Blocks [packBase, packBase+4): pack w2p; part 0 also zeroes the sentinel
//   rows t1n[N][:] and t2n[N][:] (consumed only by later dispatches).

__global__ __launch_bounds__(256) void d1p1_kernel(
        const int* __restrict__ src, const int* __restrict__ dst,
        int* __restrict__ gcursor, unsigned* __restrict__ bucket,
        int E, int nbuckets, int dblocks, int packBase,
        const float* __restrict__ X,                 // [N][64]
        const float* __restrict__ Wself,             // [64][64] k-major
        const float* __restrict__ Wneigh,            // [64][64] k-major
        const float* __restrict__ bias,              // [64]
        float* __restrict__ outA,                    // [N][64] f32 (xs)
        unsigned short* __restrict__ outB,           // [N+1][64] bf16 bits (t1n)
        int N,
        const float* __restrict__ Ws2,               // [64][32] k-major
        const float* __restrict__ Wn2,               // [64][32] k-major
        unsigned short* __restrict__ w2p,            // [8192] dense2 pack hi/lo
        unsigned short* __restrict__ t2z) {          // t2n base (for sentinel row)
    __shared__ __align__(16) int smem_i[9216];       // 36864 B union
    const int tid = threadIdx.x;

    if ((int)blockIdx.x >= packBase) {
        // ---------------- pack w2p + zero sentinel rows ----------------
        const int part = blockIdx.x - packBase;      // 0..3
        for (int i = tid; i < 16 * 64; i += 256) {   // 16 cols per part
            int n = part * 16 + (i >> 6), k = i & 63;
            float v = (n < 32) ? Ws2[k * 32 + n] : Wn2[k * 32 + (n - 32)];
            short hv = bf16hi(v);
            w2p[n * 64 + k] = (unsigned short)hv;
            w2p[4096 + n * 64 + k] = (unsigned short)bf16hi(v - bf2f(hv));
        }
        if (part == 0) {                             // zero rows at index N
            if (tid < 64) outB[(size_t)N * 64 + tid] = 0;
            if (tid >= 64 && tid < 96) t2z[(size_t)N * 32 + (tid - 64)] = 0;
        }
        return;
    }

    if ((int)blockIdx.x >= dblocks) {
        // ---------------- p1: bucket the edge list ----------------
        int* cnt   = smem_i;                         // [MAXB]
        int* cbase = smem_i + MAXB;                  // [MAXB]
        const int bid = blockIdx.x - dblocks;
        const int beg = bid * P1_CHUNK;
        const int end = min(E, beg + P1_CHUNK);
        for (int i = tid; i < nbuckets; i += 256) cnt[i] = 0;
        __syncthreads();
        for (int e = beg + tid; e < end; e += 256)
            atomicAdd(&cnt[dst[e] >> BSH], 1);
        __syncthreads();
        for (int i = tid; i < nbuckets; i += 256) {
            int c = cnt[i];
            cbase[i] = c ? atomicAdd(&gcursor[i], c) : 0;
            cnt[i] = 0;                              // reuse as local cursor
        }
        __syncthreads();
        for (int e = beg + tid; e < end; e += 256) {
            int d = dst[e];
            int r = d >> BSH;
            int p = cbase[r] + atomicAdd(&cnt[r], 1);
            if (p < CAPMAX)                          // clamp: no OOB even if skewed
                bucket[(size_t)r * CAPMAX + p] = ((unsigned)src[e] << BSH) | (unsigned)(d & (BW - 1));
        }
        return;
    }

    // ---------------- dense1: [N][64] @ [64][128] MFMA split-bf16 ----------
    // A: A[m=lane&15][k=(lane>>4)*8+j]; C/D: col=lane&15, row=(lane>>4)*4+reg.
    constexpr int NT = 8, NSELF = 4, NO = 128, HALF = 64;
    unsigned short* wh = (unsigned short*)smem_i;            // [NO*72]
    unsigned short* wl = wh + NO * 72;                       // [NO*72]
    for (int i = tid; i < NO * 64; i += 256) {
        int n = i & (NO - 1), k = i / NO;            // consecutive tid -> coalesced
        float v = (n < HALF) ? Wself[k * HALF + n] : Wneigh[k * HALF + (n - HALF)];
        short hv = bf16hi(v);
        wh[n * 72 + k] = (unsigned short)hv;
        wl[n * 72 + k] = (unsigned short)bf16hi(v - bf2f(hv));
    }

    const int lane = tid & 63;
    const int wid  = tid >> 6;
    const int m = lane & 15, quad = lane >> 4;
    const int rowblk = blockIdx.x * 128 + wid * 32;

    floatx4 acc[2][NT];
    #pragma unroll
    for (int rt = 0; rt < 2; ++rt)
        #pragma unroll
        for (int t = 0; t < NT; ++t) acc[rt][t] = (floatx4)(0.f);

    short8 ah[2][2], al[2][2];   // [rowset][k-half]
    #pragma unroll
    for (int rt = 0; rt < 2; ++rt) {
        int r = rowblk + rt * 16 + m;
        if (r >= N) r = N - 1;                       // clamped load, store guarded
        const float* xp = X + (size_t)r * 64 + quad * 8;
        #pragma unroll
        for (int h = 0; h < 2; ++h) {
            floatx4 f0 = *(const floatx4*)(xp + h * 32);
            floatx4 f1 = *(const floatx4*)(xp + h * 32 + 4);
            short8 hi, lo;
            #pragma unroll
            for (int j = 0; j < 4; ++j) {
                short hv = bf16hi(f0[j]);
                hi[j] = hv; lo[j] = bf16hi(f0[j] - bf2f(hv));
                short hv2 = bf16hi(f1[j]);
                hi[4 + j] = hv2; lo[4 + j] = bf16hi(f1[j] - bf2f(hv2));
            }
            ah[rt][h] = hi; al[rt][h] = lo;
        }
    }
    __syncthreads();                                 // weights staged

    #pragma unroll
    for (int t = 0; t < NT; ++t) {
        int n = t * 16 + m;
        const unsigned short* ph = wh + n * 72 + quad * 8;
        const unsigned short* pl = wl + n * 72 + quad * 8;
        #pragma unroll
        for (int h = 0; h < 2; ++h) {
            short8 bh = *(const short8*)(ph + h * 32);
            short8 bl = *(const short8*)(pl + h * 32);
            #pragma unroll
            for (int rt = 0; rt < 2; ++rt) {
                acc[rt][t] = __builtin_amdgcn_mfma_f32_16x16x32_bf16(ah[rt][h], bh, acc[rt][t], 0, 0, 0);
                acc[rt][t] = __builtin_amdgcn_mfma_f32_16x16x32_bf16(al[rt][h], bh, acc[rt][t], 0, 0, 0);
                acc[rt][t] = __builtin_amdgcn_mfma_f32_16x16x32_bf16(ah[rt][h], bl, acc[rt][t], 0, 0, 0);
            }
        }
    }

    #pragma unroll
    for (int rt = 0; rt < 2; ++rt) {
        #pragma unroll
        for (int t = 0; t < NT; ++t) {
            #pragma unroll
            for (int r4 = 0; r4 < 4; ++r4) {
                int row = rowblk + rt * 16 + quad * 4 + r4;
                if (row < N) {
                    if (t < NSELF) {
                        int col = t * 16 + m;
                        outA[(size_t)row * 64 + col] = acc[rt][t][r4] + bias[col];
                    } else {
                        int col = (t - NSELF) * 16 + m;
                        outB[(size_t)row * 64 + col] = (unsigned short)bf16hi(acc[rt][t][r4]);
                    }
                }
            }
        }
    }
}

// ---------------- p2: per-bucket CSR, IN PLACE ----------------
// Bucket region r holds its own CSR at base r*CAPMAX: stage entries to LDS,
// hist + scan, write rowext[n]={beg,end}, scatter sorted src ids back into
// the same region (LDS stage + barrier -> in-place safe). No cross-bucket
// prefix, no separate csr array.

__global__ __launch_bounds__(256) void p2_csr_kernel(unsigned* __restrict__ bucket,
                                                     const int* __restrict__ gcursor,
                                                     intx2* __restrict__ rowext,
                                                     int N, int nbuckets) {
    __shared__ unsigned stage[CAPMAX];   // 32 KB
    __shared__ int cnt[BW];
    __shared__ int excl[BW];
    const int r = blockIdx.x;
    const int tid = threadIdx.x;

    const int base = r * CAPMAX;
    const int sz = min(gcursor[r], CAPMAX);
    unsigned* breg = bucket + (size_t)r * CAPMAX;

    cnt[tid] = 0;
    __syncthreads();
    for (int i = tid; i < sz; i += 256) {
        unsigned v = breg[i];
        stage[i] = v;
        atomicAdd(&cnt[v & (BW - 1)], 1);
    }
    __syncthreads();
    // inclusive scan (Hillis-Steele, 1 elem/thread since BW == blockDim)
    excl[tid] = cnt[tid];
    __syncthreads();
    for (int off = 1; off < BW; off <<= 1) {
        int v0 = (tid >= off) ? excl[tid - off] : 0;
        __syncthreads();
        excl[tid] += v0;
        __syncthreads();
    }
    int node = r * BW + tid;
    if (node < N) {
        intx2 re; re[0] = base + excl[tid] - cnt[tid]; re[1] = base + excl[tid];
        rowext[node] = re;
    }
    __syncthreads();
    cnt[tid] = excl[tid] - cnt[tid];             // exclusive cursors
    __syncthreads();
    for (int i = tid; i < sz; i += 256) {        // in-place scatter (staged)
        unsigned v = stage[i];
        int p = atomicAdd(&cnt[v & (BW - 1)], 1);
        breg[p] = v >> BSH;                      // region owned by this block
    }
}

// ---------------- fused agg64 + dense2 (3-deep, zero-row sentinel) ----------
// Block = 16 nodes, 4 waves. Half-wave owns TWO nodes; 3-deep per node =
// 6 concurrent row gathers per lane; out-of-range rows redirect to the
// zeroed sentinel row N (1 cndmask per row, unconditional accumulate).

__global__ __launch_bounds__(256) void agg64_d2_kernel(
        const unsigned short* __restrict__ t1n,      // [N+1][64] bf16 bits
        const float* __restrict__ xs,                // [N][64] self+bias
        const intx2* __restrict__ rowext,            // [N] {beg,end}
        const int* __restrict__ csr_src,             // = bucket (in-place CSR)
        const unsigned short* __restrict__ w2p,      // packed hi/lo fragments
        const float* __restrict__ b2,                // [32]
        float* __restrict__ outD,                    // [N][32] (d_out)
        unsigned short* __restrict__ t2n,            // [N+1][32] bf16 bits
        int N, int CE) {                             // CE = nbuckets*CAPMAX
    __shared__ float h1s[16][H1S];                   // 4.25 KB, padded stride
    const int tid = threadIdx.x;
    const int lane = tid & 63;
    const int wid  = tid >> 6;
    const int half = lane >> 5;                      // node select within pair
    const int g = (lane >> 3) & 3;                   // 4 groups of 8 per node
    const int c = lane & 7;
    const int nbase = blockIdx.x * 16;

    const int ln0 = wid * 4 + half;                  // this half-wave's 2 nodes
    const int ln1 = ln0 + 2;
    const int n0 = nbase + ln0, n1 = nbase + ln1;
    int beg0 = 0, end0 = 0, beg1 = 0, end1 = 0;
    if (n0 < N) { intx2 re = rowext[n0]; beg0 = re[0]; end0 = re[1]; }
    if (n1 < N) { intx2 re = rowext[n1]; beg1 = re[0]; end1 = re[1]; }

    float a0[8] = {0.f, 0.f, 0.f, 0.f, 0.f, 0.f, 0.f, 0.f};
    float a1[8] = {0.f, 0.f, 0.f, 0.f, 0.f, 0.f, 0.f, 0.f};
    int j0 = beg0 + g, j1 = beg1 + g;
    const int Em1 = CE - 1;
    // prefetched index set for the current iteration (3 per node)
    int i0 = csr_src[min(j0, Em1)];
    int i1 = csr_src[min(j0 + 4, Em1)];
    int i2 = csr_src[min(j0 + 8, Em1)];
    int i3 = csr_src[min(j1, Em1)];
    int i4 = csr_src[min(j1 + 4, Em1)];
    int i5 = csr_src[min(j1 + 8, Em1)];
    while ((j0 < end0) || (j1 < end1)) {
        // redirect out-of-range rows to zeroed sentinel row N (1 cndmask each)
        int s0 = (j0     < end0) ? i0 : N;
        int s1 = (j0 + 4 < end0) ? i1 : N;
        int s2 = (j0 + 8 < end0) ? i2 : N;
        int s3 = (j1     < end1) ? i3 : N;
        int s4 = (j1 + 4 < end1) ? i4 : N;
        int s5 = (j1 + 8 < end1) ? i5 : N;
        // 6 concurrent row gathers
        ushort8v u0 = *(const ushort8v*)(t1n + (size_t)s0 * 64 + c * 8);
        ushort8v u1 = *(const ushort8v*)(t1n + (size_t)s1 * 64 + c * 8);
        ushort8v u2 = *(const ushort8v*)(t1n + (size_t)s2 * 64 + c * 8);
        ushort8v u3 = *(const ushort8v*)(t1n + (size_t)s3 * 64 + c * 8);
        ushort8v u4 = *(const ushort8v*)(t1n + (size_t)s4 * 64 + c * 8);
        ushort8v u5 = *(const ushort8v*)(t1n + (size_t)s5 * 64 + c * 8);
        // prefetch next iteration's indices (overlap gather latency)
        i0 = csr_src[min(j0 + 12, Em1)];
        i1 = csr_src[min(j0 + 16, Em1)];
        i2 = csr_src[min(j0 + 20, Em1)];
        i3 = csr_src[min(j1 + 12, Em1)];
        i4 = csr_src[min(j1 + 16, Em1)];
        i5 = csr_src[min(j1 + 20, Em1)];
        #pragma unroll
        for (int i = 0; i < 8; ++i) {                // unconditional: +0.0f when masked
            a0[i] += bits2f(u0[i]) + bits2f(u1[i]) + bits2f(u2[i]);
            a1[i] += bits2f(u3[i]) + bits2f(u4[i]) + bits2f(u5[i]);
        }
        j0 += 12; j1 += 12;
    }

    // issue tail loads now; latency hides under reduce + h1s + barrier
    const int m = lane & 15, quad = lane >> 4;
    const int coln = wid * 16 + m;
    const unsigned short* pb = w2p + coln * 64 + quad * 8;
    short8 bhf0 = *(const short8*)(pb);
    short8 bhf1 = *(const short8*)(pb + 32);
    short8 blf0 = *(const short8*)(pb + 4096);
    short8 blf1 = *(const short8*)(pb + 4096 + 32);

    floatx4 x00 = (floatx4)(0.f), x01 = (floatx4)(0.f);
    floatx4 x10 = (floatx4)(0.f), x11 = (floatx4)(0.f);
    if (g == 0) {
        if (n0 < N) {
            const float* p = xs + (size_t)n0 * 64 + c * 8;
            x00 = *(const floatx4*)p; x01 = *(const floatx4*)(p + 4);
        }
        if (n1 < N) {
            const float* p = xs + (size_t)n1 * 64 + c * 8;
            x10 = *(const floatx4*)p; x11 = *(const floatx4*)(p + 4);
        }
    }

    #pragma unroll
    for (int i = 0; i < 8; ++i) {                    // reduce over 4 groups (in-half)
        float v = a0[i];
        v += __shfl_xor(v, 8);
        v += __shfl_xor(v, 16);
        a0[i] = v;
        float w = a1[i];
        w += __shfl_xor(w, 8);
        w += __shfl_xor(w, 16);
        a1[i] = w;
    }
    if (g == 0) {                                    // 8 lanes per half write rows
        floatx4 h0, h1v;
        if (n0 < N) {
            float invd = 1.0f / fmaxf((float)(end0 - beg0), 1.0f);
            #pragma unroll
            for (int i = 0; i < 4; ++i) {
                h0[i]  = fmaxf(x00[i] + a0[i] * invd, 0.f);
                h1v[i] = fmaxf(x01[i] + a0[4 + i] * invd, 0.f);
            }
        } else { h0 = (floatx4)(0.f); h1v = (floatx4)(0.f); }
        *(floatx4*)&h1s[ln0][c * 8]     = h0;
        *(floatx4*)&h1s[ln0][c * 8 + 4] = h1v;
        if (n1 < N) {
            float invd = 1.0f / fmaxf((float)(end1 - beg1), 1.0f);
            #pragma unroll
            for (int i = 0; i < 4; ++i) {
                h0[i]  = fmaxf(x10[i] + a1[i] * invd, 0.f);
                h1v[i] = fmaxf(x11[i] + a1[4 + i] * invd, 0.f);
            }
        } else { h0 = (floatx4)(0.f); h1v = (floatx4)(0.f); }
        *(floatx4*)&h1s[ln1][c * 8]     = h0;
        *(floatx4*)&h1s[ln1][c * 8 + 4] = h1v;
    }
    __syncthreads();                                 // h1 tile ready

    // dense2: wave wid -> output cols wid*16 .. wid*16+15
    short8 ah[2], al[2];                             // A = h1s, split hi/lo
    #pragma unroll
    for (int h = 0; h < 2; ++h) {
        const float* hp = &h1s[m][quad * 8 + h * 32];
        floatx4 f0 = *(const floatx4*)hp;
        floatx4 f1 = *(const floatx4*)(hp + 4);
        short8 hi, lo;
        #pragma unroll
        for (int j = 0; j < 4; ++j) {
            short hv = bf16hi(f0[j]);
            hi[j] = hv; lo[j] = bf16hi(f0[j] - bf2f(hv));
            short hv2 = bf16hi(f1[j]);
            hi[4 + j] = hv2; lo[4 + j] = bf16hi(f1[j] - bf2f(hv2));
        }
        ah[h] = hi; al[h] = lo;
    }
    floatx4 acc2 = (floatx4)(0.f);
    acc2 = __builtin_amdgcn_mfma_f32_16x16x32_bf16(ah[0], bhf0, acc2, 0, 0, 0);
    acc2 = __builtin_amdgcn_mfma_f32_16x16x32_bf16(al[0], bhf0, acc2, 0, 0, 0);
    acc2 = __builtin_amdgcn_mfma_f32_16x16x32_bf16(ah[0], blf0, acc2, 0, 0, 0);
    acc2 = __builtin_amdgcn_mfma_f32_16x16x32_bf16(ah[1], bhf1, acc2, 0, 0, 0);
    acc2 = __builtin_amdgcn_mfma_f32_16x16x32_bf16(al[1], bhf1, acc2, 0, 0, 0);
    acc2 = __builtin_amdgcn_mfma_f32_16x16x32_bf16(ah[1], blf1, acc2, 0, 0, 0);
    #pragma unroll
    for (int r4 = 0; r4 < 4; ++r4) {
        int node = nbase + quad * 4 + r4;
        if (node < N) {
            if (coln < 32) outD[(size_t)node * 32 + coln] = acc2[r4] + b2[coln];
            else t2n[(size_t)node * 32 + (coln - 32)] = (unsigned short)bf16hi(acc2[r4]);
        }
    }
}

// ---------------- agg32: d_out += mean t2n[src], in place (3-deep) ----------
// 16-lane group per node (4 edge-groups x 3-deep), zero-row sentinel.

__global__ __launch_bounds__(256) void agg32_kernel(float* io,  // [N][32] (d_out)
                                                    const unsigned short* __restrict__ t2n,
                                                    const intx2* __restrict__ rowext,
                                                    const int* __restrict__ csr_src,
                                                    int N, int CE) {
    const int tid = threadIdx.x;
    const int lane = tid & 63;
    const int wid = tid >> 6;
    const int slot = lane >> 4;                      // 4 nodes per wave
    const int g = (lane >> 2) & 3;                   // 4 edge-groups per node
    const int c = lane & 3;                          // 16B chunk of 64B row
    const int n = blockIdx.x * 16 + wid * 4 + slot;

    int beg = 0, end = 0;
    if (n < N) { intx2 re = rowext[n]; beg = re[0]; end = re[1]; }

    // hoist in-place read: overlaps the gather chain instead of trailing it
    floatx4 s0v = (floatx4)(0.f), s1v = (floatx4)(0.f);
    size_t o = (size_t)n * 32 + c * 8;
    if (n < N && g == 0) {
        s0v = *(const floatx4*)(io + o);
        s1v = *(const floatx4*)(io + o + 4);
    }

    float acc[8] = {0.f, 0.f, 0.f, 0.f, 0.f, 0.f, 0.f, 0.f};
    const int Em1 = CE - 1;
    for (int j = beg + g; j < end; j += 12) {
        int r0 = csr_src[j];                         // j < end <= CE guaranteed
        int r1 = csr_src[min(j + 4, Em1)];
        int r2 = csr_src[min(j + 8, Em1)];
        int s0 = r0;                                 // always in range
        int s1 = (j + 4 < end) ? r1 : N;             // sentinel redirect
        int s2 = (j + 8 < end) ? r2 : N;
        ushort8v u0 = *(const ushort8v*)(t2n + (size_t)s0 * 32 + c * 8);
        ushort8v u1 = *(const ushort8v*)(t2n + (size_t)s1 * 32 + c * 8);
        ushort8v u2 = *(const ushort8v*)(t2n + (size_t)s2 * 32 + c * 8);
        #pragma unroll
        for (int i = 0; i < 8; ++i)                  // unconditional accumulate
            acc[i] += bits2f(u0[i]) + bits2f(u1[i]) + bits2f(u2[i]);
    }
    #pragma unroll
    for (int i = 0; i < 8; ++i) {                    // reduce over 4 groups (16-lane)
        float v = acc[i];
        v += __shfl_xor(v, 4);
        v += __shfl_xor(v, 8);
        acc[i] = v;
    }
    if (n < N && g == 0) {
        float inv = 1.0f / fmaxf((float)(end - beg), 1.0f);
        floatx4 r0, r1;
        #pragma unroll
        for (int i = 0; i < 4; ++i) {
            r0[i] = s0v[i] + acc[i] * inv;
            r1[i] = s1v[i] + acc[4 + i] * inv;
        }
        *(floatx4*)(io + o) = r0;
        *(floatx4*)(io + o + 4) = r1;
    }
}

// ---------------- fallback (round-2 atomic path) ----------------

__global__ __launch_bounds__(256) void deg_kernel(const int* __restrict__ dst,
                                                  float* __restrict__ deg, int E) {
    int e = blockIdx.x * blockDim.x + threadIdx.x;
    if (e < E) atomicAdd(&deg[dst[e]], 1.0f);
}

__global__ __launch_bounds__(256) void agg_atomic_kernel(const float* __restrict__ feats,
                                                         const int* __restrict__ src,
                                                         const int* __restrict__ dst,
                                                         float* __restrict__ agg, int E) {
    int tid = blockIdx.x * blockDim.x + threadIdx.x;
    if (tid >= E * NF) return;
    int e = tid >> 6, f = tid & 63;
    atomicAdd(&agg[(size_t)dst[e] * NF + f], feats[(size_t)src[e] * NF + f]);
}

__global__ __launch_bounds__(256) void layer1_fb_kernel(const float* __restrict__ x,
                                                        const float* __restrict__ agg,
                                                        const float* __restrict__ deg,
                                                        const float* __restrict__ Wself,
                                                        const float* __restrict__ Wneigh,
                                                        const float* __restrict__ b,
                                                        float* __restrict__ h1, int N) {
    int tid = blockIdx.x * blockDim.x + threadIdx.x;
    if (tid >= N * NF) return;
    int n = tid >> 6, c = tid & 63;
    float inv = 1.0f / fmaxf(deg[n], 1.0f);
    const float* xrow = x + (size_t)n * NF;
    const float* arow = agg + (size_t)n * NF;
    float acc = b[c];
    #pragma unroll
    for (int k = 0; k < NF; ++k) {
        acc += xrow[k] * Wself[k * NF + c];
        acc += (arow[k] * inv) * Wneigh[k * NF + c];
    }
    h1[tid] = fmaxf(acc, 0.f);
}

__global__ __launch_bounds__(256) void layer2_fb_kernel(const float* __restrict__ h1,
                                                        const float* __restrict__ agg,
                                                        const float* __restrict__ deg,
                                                        const float* __restrict__ Wself,
                                                        const float* __restrict__ Wneigh,
                                                        const float* __restrict__ b,
                                                        float* __restrict__ out, int N) {
    int tid = blockIdx.x * blockDim.x + threadIdx.x;
    if (tid >= N * 32) return;
    int n = tid >> 5, c = tid & 31;
    float inv = 1.0f / fmaxf(deg[n], 1.0f);
    const float* hrow = h1 + (size_t)n * NF;
    const float* arow = agg + (size_t)n * NF;
    float acc = b[c];
    #pragma unroll
    for (int k = 0; k < NF; ++k) {
        acc += hrow[k] * Wself[k * 32 + c];
        acc += (arow[k] * inv) * Wneigh[k * 32 + c];
    }
    out[tid] = acc;
}

// ---------------- launch ----------------

extern "C" void kernel_launch(void* const* d_in, const int* in_sizes, int n_in,
                              void* d_out, int out_size, void* d_ws, size_t ws_size,
                              hipStream_t stream) {
    const float* x        = (const float*)d_in[0];
    const int*   src      = (const int*)d_in[1];
    const int*   dst      = (const int*)d_in[2];
    const float* W_self1  = (const float*)d_in[3];
    const float* W_neigh1 = (const float*)d_in[4];
    const float* b1       = (const float*)d_in[5];
    const float* W_self2  = (const float*)d_in[6];
    const float* W_neigh2 = (const float*)d_in[7];
    const float* b2       = (const float*)d_in[8];
    float* out = (float*)d_out;

    const int N = in_sizes[0] / NF;          // 100000
    const int E = in_sizes[1];               // 1250000
    const int nbuckets = (N + BW - 1) / BW;  // 391

    // ws layout; gather tables 128B-aligned (round-10 proven). t1n/t2n have
    // one extra SENTINEL row at index N. bucket region doubles as the CSR
    // (p2 sorts in place); rowext[n] = {beg,end} into that region.
    int* gcursor   = (int*)d_ws;                      // [MAXB]
    unsigned short* w2p = (unsigned short*)(gcursor + MAXB);  // [8192] (16 KB)
    intx2* rowext  = (intx2*)(w2p + 8192);            // [N] {beg,end}
    uintptr_t pa = (uintptr_t)(rowext + N);
    pa = (pa + 127) & ~(uintptr_t)127;                // 128B align
    float* bufA = (float*)pa;                         // [N][64] f32 (xs)
    unsigned short* t1n = (unsigned short*)(bufA + (size_t)N * NF);  // [N+1][64] bf16
    unsigned short* t2n = t1n + (size_t)(N + 1) * NF;                // [N+1][32] bf16
    uintptr_t pb = ((uintptr_t)(t2n + (size_t)(N + 1) * 32) + 63) & ~(uintptr_t)63;
    unsigned* bucket = (unsigned*)pb;                 // [nbuckets][CAPMAX] -> CSR
    size_t need = (size_t)((char*)(bucket + (size_t)nbuckets * CAPMAX) - (char*)d_ws);

    bool fast = ws_size >= need
             && E > 0 && N > 0
             && nbuckets <= MAXB
             && (size_t)E * 2 / (size_t)nbuckets <= CAPMAX       // 2x headroom over mean
             && N < (1 << 24)                                    // src fits in 24 bits
             && out_size >= N * 32;

    if (fast) {
        const int dblocks  = (N + 127) / 128;                    // 782
        const int p1blocks = (E + P1_CHUNK - 1) / P1_CHUNK;      // 611
        const int CE = nbuckets * CAPMAX;
        hipMemsetAsync(gcursor, 0, MAXB * sizeof(int), stream);
        d1p1_kernel<<<dblocks + p1blocks + 4, 256, 0, stream>>>(
            src, dst, gcursor, bucket, E, nbuckets, dblocks,
            dblocks + p1blocks,
            x, W_self1, W_neigh1, b1, bufA, t1n, N,
            W_self2, W_neigh2, w2p, t2n);
        p2_csr_kernel<<<nbuckets, 256, 0, stream>>>(bucket, gcursor,
                                                    rowext, N, nbuckets);
        agg64_d2_kernel<<<(N + 15) / 16, 256, 0, stream>>>(
            t1n, bufA, rowext, (const int*)bucket, w2p, b2, out, t2n, N, CE);
        agg32_kernel<<<(N + 15) / 16, 256, 0, stream>>>(out, t2n,
                                                        rowext, (const int*)bucket, N, CE);
    } else {
        // fallback: atomic path (~51.6 MB)
        float* deg = (float*)d_ws;
        float* agg = deg + N;
        float* h1  = agg + (size_t)N * NF;
        hipMemsetAsync(deg, 0, (size_t)(N + (size_t)N * NF) * sizeof(float), stream);
        deg_kernel<<<(E + 255) / 256, 256, 0, stream>>>(dst, deg, E);
        int at = E * NF;
        agg_atomic_kernel<<<(at + 255) / 256, 256, 0, stream>>>(x, src, dst, agg, E);
        layer1_fb_kernel<<<(N * NF + 255) / 256, 256, 0, stream>>>(x, agg, deg, W_self1,
                                                                   W_neigh1, b1, h1, N);
        hipMemsetAsync(agg, 0, (size_t)N * NF * sizeof(float), stream);
        agg_atomic_kernel<<<(at + 255) / 256, 256, 0, stream>>>(h1, src, dst, agg, E);
        layer2_fb_kernel<<<(N * 32 + 255) / 256, 256, 0, stream>>>(h1, agg, deg, W_self2,
                                                                   W_neigh2, b2, out, N);
    }
}